// Round 3
// baseline (611.694 us; speedup 1.0000x reference)
//
#include <hip/hip_runtime.h>
#include <math.h>

#define D_DIM 512

constexpr int MT = 64;    // rows per block
constexpr int NT = 128;   // col chunk
constexpr int KT = 64;    // k chunk

// ait[m] = sum_e tanh((x@W)[m,e] + b[e]) * u[e]   (uit never materialized)
__global__ __launch_bounds__(256) void gemm_ait_kernel(
    const float* __restrict__ x, const float* __restrict__ W,
    const float* __restrict__ bias, const float* __restrict__ u,
    float* __restrict__ ait)
{
    __shared__ float xs[MT][KT + 4];    // stride 68 floats
    __shared__ float wsh[KT][NT + 4];   // stride 132 floats

    const int tid = threadIdx.x;
    const int tx = tid & 15;            // col group
    const int ty = tid >> 4;            // row group
    const int m0 = blockIdx.x * MT;

    float rowsum[4] = {0.f, 0.f, 0.f, 0.f};

    for (int e0 = 0; e0 < D_DIM; e0 += NT) {
        float acc[4][8];
        #pragma unroll
        for (int i = 0; i < 4; ++i)
            #pragma unroll
            for (int j = 0; j < 8; ++j) acc[i][j] = 0.f;

        for (int kc = 0; kc < D_DIM; kc += KT) {
            #pragma unroll
            for (int i = 0; i < 4; ++i) {
                int idx = tid + i * 256;        // 0..1023
                int r = idx >> 4;
                int c = (idx & 15) * 4;
                float4 v = *(const float4*)(x + (size_t)(m0 + r) * D_DIM + kc + c);
                *(float4*)&xs[r][c] = v;
            }
            #pragma unroll
            for (int i = 0; i < 8; ++i) {
                int idx = tid + i * 256;        // 0..2047
                int r = idx >> 5;
                int c = (idx & 31) * 4;
                float4 v = *(const float4*)(W + (size_t)(kc + r) * D_DIM + e0 + c);
                *(float4*)&wsh[r][c] = v;
            }
            __syncthreads();

            #pragma unroll 4
            for (int k = 0; k < KT; ++k) {
                float xv[4];
                #pragma unroll
                for (int i = 0; i < 4; ++i) xv[i] = xs[ty * 4 + i][k];
                float4 w0 = *(const float4*)&wsh[k][tx * 8];
                float4 w1 = *(const float4*)&wsh[k][tx * 8 + 4];
                #pragma unroll
                for (int i = 0; i < 4; ++i) {
                    acc[i][0] += xv[i] * w0.x;
                    acc[i][1] += xv[i] * w0.y;
                    acc[i][2] += xv[i] * w0.z;
                    acc[i][3] += xv[i] * w0.w;
                    acc[i][4] += xv[i] * w1.x;
                    acc[i][5] += xv[i] * w1.y;
                    acc[i][6] += xv[i] * w1.z;
                    acc[i][7] += xv[i] * w1.w;
                }
            }
            __syncthreads();
        }

        // fused epilogue: tanh + dot with u
        #pragma unroll
        for (int j = 0; j < 8; ++j) {
            int e = e0 + tx * 8 + j;
            float be = bias[e];
            float ue = u[e];
            #pragma unroll
            for (int i = 0; i < 4; ++i) {
                float v = tanhf(acc[i][j] + be);
                rowsum[i] += v * ue;
            }
        }
    }

    // reduce rowsum across the 16 tx threads sharing each row
    float* red = &xs[0][0];   // reuse LDS (all prior reads fenced by last sync)
    #pragma unroll
    for (int i = 0; i < 4; ++i) red[(ty * 4 + i) * 16 + tx] = rowsum[i];
    __syncthreads();
    if (tid < 64) {
        float s = 0.f;
        #pragma unroll
        for (int j = 0; j < 16; ++j) s += red[tid * 16 + j];
        ait[m0 + tid] = s;
    }
}

// in-place: a[b,t] = exp(ait[b,t]) / (sum_t exp + eps)
__global__ __launch_bounds__(256) void softmax_kernel(
    float* __restrict__ ait, int T)
{
    const int b = blockIdx.x;
    float* p = ait + (size_t)b * T;
    const int tid = threadIdx.x;

    float ev[8];
    float local = 0.f;
    #pragma unroll
    for (int i = 0; i < 8; ++i) {
        ev[i] = expf(p[tid + i * 256]);
        local += ev[i];
    }
    #pragma unroll
    for (int off = 32; off > 0; off >>= 1)
        local += __shfl_down(local, off, 64);

    __shared__ float wsum[4];
    const int wave = tid >> 6, lane = tid & 63;
    if (lane == 0) wsum[wave] = local;
    __syncthreads();
    float total = wsum[0] + wsum[1] + wsum[2] + wsum[3];
    float inv = 1.0f / (total + 1e-7f);
    #pragma unroll
    for (int i = 0; i < 8; ++i) p[tid + i * 256] = ev[i] * inv;
}

// partial[bc, d] = sum over a 256-t chunk of x[b,t,d] * a[b,t]
__global__ __launch_bounds__(256) void pool_partial_kernel(
    const float* __restrict__ x, const float* __restrict__ a,
    float* __restrict__ partial, int T)
{
    const int chunks = T >> 8;               // 256 t per block
    const int b = blockIdx.x / chunks;
    const int c = blockIdx.x % chunks;
    const int tid = threadIdx.x;
    const int d = tid * 2;
    const int t0 = c * 256;

    const float* xp = x + ((size_t)b * T + t0) * D_DIM + d;
    const float* ap = a + (size_t)b * T + t0;

    float2 acc = {0.f, 0.f};
    for (int t = 0; t < 256; ++t) {
        float s = ap[t];
        float2 xv = *(const float2*)(xp + (size_t)t * D_DIM);
        acc.x += xv.x * s;
        acc.y += xv.y * s;
    }
    *(float2*)(partial + (size_t)blockIdx.x * D_DIM + d) = acc;
}

// out[b,d] = sum_c partial[b,c,d]
__global__ __launch_bounds__(256) void pool_reduce_kernel(
    const float* __restrict__ partial, float* __restrict__ out, int chunks)
{
    const int b = blockIdx.x;
    const int tid = threadIdx.x;
    const int d = tid * 2;
    float2 acc = {0.f, 0.f};
    for (int c = 0; c < chunks; ++c) {
        float2 v = *(const float2*)(partial + ((size_t)b * chunks + c) * D_DIM + d);
        acc.x += v.x;
        acc.y += v.y;
    }
    *(float2*)(out + (size_t)b * D_DIM + d) = acc;
}

// fallback pool (no partial workspace): atomics into zeroed d_out
__global__ __launch_bounds__(256) void pool_atomic_kernel(
    const float* __restrict__ x, const float* __restrict__ a,
    float* __restrict__ out, int T)
{
    const int chunks = T >> 8;
    const int b = blockIdx.x / chunks;
    const int c = blockIdx.x % chunks;
    const int tid = threadIdx.x;
    const int d = tid * 2;
    const int t0 = c * 256;

    const float* xp = x + ((size_t)b * T + t0) * D_DIM + d;
    const float* ap = a + (size_t)b * T + t0;

    float2 acc = {0.f, 0.f};
    for (int t = 0; t < 256; ++t) {
        float s = ap[t];
        float2 xv = *(const float2*)(xp + (size_t)t * D_DIM);
        acc.x += xv.x * s;
        acc.y += xv.y * s;
    }
    float* o = out + (size_t)b * D_DIM + d;
    atomicAdd(o + 0, acc.x);
    atomicAdd(o + 1, acc.y);
}

extern "C" void kernel_launch(void* const* d_in, const int* in_sizes, int n_in,
                              void* d_out, int out_size, void* d_ws, size_t ws_size,
                              hipStream_t stream)
{
    const float* x    = (const float*)d_in[0];
    const float* W    = (const float*)d_in[1];
    const float* bias = (const float*)d_in[2];
    const float* u    = (const float*)d_in[3];
    float* out = (float*)d_out;

    const int Dd = in_sizes[2];          // 512
    const int M  = in_sizes[0] / Dd;     // B*T = 65536
    const int B  = out_size / Dd;        // 32
    const int T  = M / B;                // 2048
    const int chunks = T >> 8;           // 8

    float* ait = (float*)d_ws;           // M floats (reused in-place as `a`)
    float* partial = ait + M;            // B*chunks*D floats

    const size_t need_ait  = (size_t)M * sizeof(float);
    const size_t need_part = need_ait + (size_t)B * chunks * Dd * sizeof(float);

    // ait is mandatory scratch; if even that doesn't fit we cannot proceed
    // correctly — but 256 KiB is far below any plausible ws allocation.
    gemm_ait_kernel<<<dim3(M / MT), dim3(256), 0, stream>>>(x, W, bias, u, ait);
    softmax_kernel<<<dim3(B), dim3(256), 0, stream>>>(ait, T);

    if (ws_size >= need_part) {
        pool_partial_kernel<<<dim3(B * chunks), dim3(256), 0, stream>>>(x, ait, partial, T);
        pool_reduce_kernel<<<dim3(B), dim3(256), 0, stream>>>(partial, out, chunks);
    } else {
        hipMemsetAsync(d_out, 0, (size_t)out_size * sizeof(float), stream);
        pool_atomic_kernel<<<dim3(B * chunks), dim3(256), 0, stream>>>(x, ait, out, T);
    }
}

// Round 5
// 288.105 us; speedup vs baseline: 2.1232x; 2.1232x over previous
//
#include <hip/hip_runtime.h>
#include <math.h>

#define D_DIM 512

typedef short short8v __attribute__((ext_vector_type(8)));
typedef unsigned short ushort8v __attribute__((ext_vector_type(8)));
typedef float f32x16 __attribute__((ext_vector_type(16)));

__device__ inline unsigned short f2bf(float f) {
    union { float f; unsigned int u; } a; a.f = f;
    unsigned int u = a.u;
    unsigned int r = (u + 0x7fffu + ((u >> 16) & 1u)) >> 16;  // RNE
    return (unsigned short)r;
}

// ---- W -> Wb: transpose to [e][k] and convert to bf16 ----
__global__ __launch_bounds__(256) void wt_kernel(const float* __restrict__ W,
                                                 unsigned short* __restrict__ Wb) {
    int g = blockIdx.x * 256 + threadIdx.x;   // 0 .. 512*128-1
    int k = g >> 7;                           // W row (coalesced float4 read)
    int e4 = (g & 127) * 4;
    float4 v = *(const float4*)(W + (size_t)k * D_DIM + e4);
    Wb[(size_t)(e4 + 0) * D_DIM + k] = f2bf(v.x);
    Wb[(size_t)(e4 + 1) * D_DIM + k] = f2bf(v.y);
    Wb[(size_t)(e4 + 2) * D_DIM + k] = f2bf(v.z);
    Wb[(size_t)(e4 + 3) * D_DIM + k] = f2bf(v.w);
}

// ---- MFMA GEMM + fused tanh/dot-u epilogue ----
// block: 256 thr = 4 waves; tile 64 rows x 512 cols; K staged in 32-chunks.
// wave w covers cols [w*128, w*128+128) as 2x4 tiles of 32x32 (mfma 32x32x16).
constexpr int LDE = 40;   // LDS row stride in bf16 elems = 80 B (16B-aligned)

__global__ __launch_bounds__(256, 2) void gemm_ait_mfma(
    const float* __restrict__ x, const unsigned short* __restrict__ Wb,
    const float* __restrict__ bias, const float* __restrict__ u,
    float* __restrict__ ait)
{
    __shared__ __align__(16) unsigned short xs[64 * LDE];
    __shared__ __align__(16) unsigned short wsh[512 * LDE];
    __shared__ float rowpart[4][64];

    const int tid  = threadIdx.x;
    const int wave = tid >> 6;
    const int lane = tid & 63;
    const int half = lane >> 5;      // k-half selector
    const int nl   = lane & 31;      // row/col within 32-tile
    const int m0   = blockIdx.x * 64;

    f32x16 acc[2][4];
    #pragma unroll
    for (int mi = 0; mi < 2; ++mi)
        #pragma unroll
        for (int ni = 0; ni < 4; ++ni)
            #pragma unroll
            for (int r = 0; r < 16; ++r) acc[mi][ni][r] = 0.f;

    const int xr = tid >> 2;     // x row 0..63
    const int xc = tid & 3;      // 8-elem chunk

    for (int kk = 0; kk < D_DIM; kk += 32) {
        // stage x tile (fp32 -> bf16 in-register)
        {
            const float* xp = x + (size_t)(m0 + xr) * D_DIM + kk + xc * 8;
            float4 a0 = *(const float4*)xp;
            float4 a1 = *(const float4*)(xp + 4);
            ushort8v pk;
            pk[0] = f2bf(a0.x); pk[1] = f2bf(a0.y); pk[2] = f2bf(a0.z); pk[3] = f2bf(a0.w);
            pk[4] = f2bf(a1.x); pk[5] = f2bf(a1.y); pk[6] = f2bf(a1.z); pk[7] = f2bf(a1.w);
            *(ushort8v*)&xs[xr * LDE + xc * 8] = pk;
        }
        // stage W tile: 512 e-rows x 32 k (bf16, already [e][k] in Wb)
        #pragma unroll
        for (int p = 0; p < 8; ++p) {
            int chunk = tid + p * 256;        // 0..2047 16B-chunks
            int e  = chunk >> 2;
            int ci = chunk & 3;
            ushort8v wv = *(const ushort8v*)&Wb[(size_t)e * D_DIM + kk + ci * 8];
            *(ushort8v*)&wsh[e * LDE + ci * 8] = wv;
        }
        __syncthreads();

        #pragma unroll
        for (int ks = 0; ks < 2; ++ks) {      // two K=16 steps per stage
            short8v af[2], bfr[4];
            #pragma unroll
            for (int mi = 0; mi < 2; ++mi)
                af[mi] = *(const short8v*)&xs[(mi * 32 + nl) * LDE + ks * 16 + half * 8];
            #pragma unroll
            for (int ni = 0; ni < 4; ++ni)
                bfr[ni] = *(const short8v*)&wsh[(wave * 128 + ni * 32 + nl) * LDE + ks * 16 + half * 8];
            #pragma unroll
            for (int mi = 0; mi < 2; ++mi)
                #pragma unroll
                for (int ni = 0; ni < 4; ++ni)
                    acc[mi][ni] = __builtin_amdgcn_mfma_f32_32x32x16_bf16(
                        af[mi], bfr[ni], acc[mi][ni], 0, 0, 0);
        }
        __syncthreads();
    }

    // epilogue: ait[m] = sum_e tanh(C[m][e]+bias[e]) * u[e]
    // C/D layout (verified m74/m101): col = lane&31, row = (reg&3) + 8*(reg>>2) + 4*(lane>>5)
    float rowsum[2][16];
    #pragma unroll
    for (int mi = 0; mi < 2; ++mi)
        #pragma unroll
        for (int r = 0; r < 16; ++r) rowsum[mi][r] = 0.f;

    #pragma unroll
    for (int mi = 0; mi < 2; ++mi) {
        #pragma unroll
        for (int ni = 0; ni < 4; ++ni) {
            int col = wave * 128 + ni * 32 + nl;
            float be = bias[col], ue = u[col];
            #pragma unroll
            for (int r = 0; r < 16; ++r)
                rowsum[mi][r] += tanhf(acc[mi][ni][r] + be) * ue;
        }
    }
    // reduce across the 32 column-lanes (stays within each 32-lane half)
    #pragma unroll
    for (int mi = 0; mi < 2; ++mi)
        #pragma unroll
        for (int r = 0; r < 16; ++r) {
            float v = rowsum[mi][r];
            v += __shfl_xor(v, 1, 64);
            v += __shfl_xor(v, 2, 64);
            v += __shfl_xor(v, 4, 64);
            v += __shfl_xor(v, 8, 64);
            v += __shfl_xor(v, 16, 64);
            rowsum[mi][r] = v;
        }
    if (nl == 0) {
        #pragma unroll
        for (int mi = 0; mi < 2; ++mi)
            #pragma unroll
            for (int r = 0; r < 16; ++r) {
                int row = mi * 32 + (r & 3) + 8 * (r >> 2) + 4 * half;
                rowpart[wave][row] = rowsum[mi][r];
            }
    }
    __syncthreads();
    if (tid < 64)
        ait[m0 + tid] = rowpart[0][tid] + rowpart[1][tid] + rowpart[2][tid] + rowpart[3][tid];
}

// ---- fp32 fallback GEMM (only if workspace is unexpectedly tiny) ----
__global__ __launch_bounds__(256) void gemm_ait_f32(
    const float* __restrict__ x, const float* __restrict__ W,
    const float* __restrict__ bias, const float* __restrict__ u,
    float* __restrict__ ait)
{
    __shared__ float xsf[64][68];
    __shared__ float wshf[64][132];
    const int tid = threadIdx.x;
    const int tx = tid & 15, ty = tid >> 4;
    const int m0 = blockIdx.x * 64;
    float rowsum[4] = {0.f, 0.f, 0.f, 0.f};
    for (int e0 = 0; e0 < D_DIM; e0 += 128) {
        float acc[4][8];
        #pragma unroll
        for (int i = 0; i < 4; ++i)
            #pragma unroll
            for (int j = 0; j < 8; ++j) acc[i][j] = 0.f;
        for (int kc = 0; kc < D_DIM; kc += 64) {
            #pragma unroll
            for (int i = 0; i < 4; ++i) {
                int idx = tid + i * 256;
                int r = idx >> 4, c = (idx & 15) * 4;
                *(float4*)&xsf[r][c] = *(const float4*)(x + (size_t)(m0 + r) * D_DIM + kc + c);
            }
            #pragma unroll
            for (int i = 0; i < 8; ++i) {
                int idx = tid + i * 256;
                int r = idx >> 5, c = (idx & 31) * 4;
                *(float4*)&wshf[r][c] = *(const float4*)(W + (size_t)(kc + r) * D_DIM + e0 + c);
            }
            __syncthreads();
            #pragma unroll 4
            for (int k = 0; k < 64; ++k) {
                float xv[4];
                #pragma unroll
                for (int i = 0; i < 4; ++i) xv[i] = xsf[ty * 4 + i][k];
                float4 w0 = *(const float4*)&wshf[k][tx * 8];
                float4 w1 = *(const float4*)&wshf[k][tx * 8 + 4];
                #pragma unroll
                for (int i = 0; i < 4; ++i) {
                    acc[i][0] += xv[i] * w0.x; acc[i][1] += xv[i] * w0.y;
                    acc[i][2] += xv[i] * w0.z; acc[i][3] += xv[i] * w0.w;
                    acc[i][4] += xv[i] * w1.x; acc[i][5] += xv[i] * w1.y;
                    acc[i][6] += xv[i] * w1.z; acc[i][7] += xv[i] * w1.w;
                }
            }
            __syncthreads();
        }
        #pragma unroll
        for (int j = 0; j < 8; ++j) {
            int e = e0 + tx * 8 + j;
            float be = bias[e], ue = u[e];
            #pragma unroll
            for (int i = 0; i < 4; ++i) rowsum[i] += tanhf(acc[i][j] + be) * ue;
        }
    }
    float* red = &xsf[0][0];
    #pragma unroll
    for (int i = 0; i < 4; ++i) red[(ty * 4 + i) * 16 + tx] = rowsum[i];
    __syncthreads();
    if (tid < 64) {
        float s = 0.f;
        #pragma unroll
        for (int j = 0; j < 16; ++j) s += red[tid * 16 + j];
        ait[m0 + tid] = s;
    }
}

// ---- softmax over T (in-place, plain exp + eps, matching reference) ----
__global__ __launch_bounds__(256) void softmax_kernel(float* __restrict__ ait, int T)
{
    const int b = blockIdx.x;
    float* p = ait + (size_t)b * T;
    const int tid = threadIdx.x;
    float ev[8];
    float local = 0.f;
    #pragma unroll
    for (int i = 0; i < 8; ++i) {
        ev[i] = expf(p[tid + i * 256]);
        local += ev[i];
    }
    #pragma unroll
    for (int off = 32; off > 0; off >>= 1)
        local += __shfl_down(local, off, 64);
    __shared__ float wsum[4];
    const int wv = tid >> 6, lane = tid & 63;
    if (lane == 0) wsum[wv] = local;
    __syncthreads();
    float total = wsum[0] + wsum[1] + wsum[2] + wsum[3];
    float inv = 1.0f / (total + 1e-7f);
    #pragma unroll
    for (int i = 0; i < 8; ++i) p[tid + i * 256] = ev[i] * inv;
}

// ---- pooling: partial sums over 256-t chunks (float4 loads) ----
__global__ __launch_bounds__(256) void pool_partial_kernel(
    const float* __restrict__ x, const float* __restrict__ a,
    float* __restrict__ partial, int T)
{
    const int chunks = T >> 8;
    const int b = blockIdx.x / chunks;
    const int c = blockIdx.x % chunks;
    const int tid = threadIdx.x;
    const int th = tid >> 7;                 // 2 t-streams
    const int d = (tid & 127) * 4;
    const int t0 = c * 256 + th * 128;

    const float* xp = x + ((size_t)b * T + t0) * D_DIM + d;
    const float* ap = a + (size_t)b * T + t0;

    float4 acc = {0.f, 0.f, 0.f, 0.f};
    for (int t = 0; t < 128; ++t) {
        float s = ap[t];
        float4 xv = *(const float4*)(xp + (size_t)t * D_DIM);
        acc.x += xv.x * s; acc.y += xv.y * s;
        acc.z += xv.z * s; acc.w += xv.w * s;
    }
    __shared__ float4 tmp[128];
    if (th == 1) tmp[tid & 127] = acc;
    __syncthreads();
    if (th == 0) {
        float4 o = tmp[tid];
        acc.x += o.x; acc.y += o.y; acc.z += o.z; acc.w += o.w;
        *(float4*)(partial + (size_t)blockIdx.x * D_DIM + d) = acc;
    }
}

__global__ __launch_bounds__(256) void pool_reduce_kernel(
    const float* __restrict__ partial, float* __restrict__ out, int chunks)
{
    const int b = blockIdx.x;
    const int tid = threadIdx.x;
    const int d = tid * 2;
    float2 acc = {0.f, 0.f};
    for (int c = 0; c < chunks; ++c) {
        float2 v = *(const float2*)(partial + ((size_t)b * chunks + c) * D_DIM + d);
        acc.x += v.x; acc.y += v.y;
    }
    *(float2*)(out + (size_t)b * D_DIM + d) = acc;
}

__global__ __launch_bounds__(256) void pool_atomic_kernel(
    const float* __restrict__ x, const float* __restrict__ a,
    float* __restrict__ out, int T)
{
    const int chunks = T >> 8;
    const int b = blockIdx.x / chunks;
    const int c = blockIdx.x % chunks;
    const int tid = threadIdx.x;
    const int d = tid * 2;
    const int t0 = c * 256;
    const float* xp = x + ((size_t)b * T + t0) * D_DIM + d;
    const float* ap = a + (size_t)b * T + t0;
    float2 acc = {0.f, 0.f};
    for (int t = 0; t < 256; ++t) {
        float s = ap[t];
        float2 xv = *(const float2*)(xp + (size_t)t * D_DIM);
        acc.x += xv.x * s; acc.y += xv.y * s;
    }
    float* o = out + (size_t)b * D_DIM + d;
    atomicAdd(o + 0, acc.x);
    atomicAdd(o + 1, acc.y);
}

extern "C" void kernel_launch(void* const* d_in, const int* in_sizes, int n_in,
                              void* d_out, int out_size, void* d_ws, size_t ws_size,
                              hipStream_t stream)
{
    const float* x    = (const float*)d_in[0];
    const float* W    = (const float*)d_in[1];
    const float* bias = (const float*)d_in[2];
    const float* u    = (const float*)d_in[3];
    float* out = (float*)d_out;

    const int Dd = in_sizes[2];          // 512
    const int M  = in_sizes[0] / Dd;     // 65536
    const int B  = out_size / Dd;        // 32
    const int T  = M / B;                // 2048
    const int chunks = T >> 8;           // 8

    const size_t wb_bytes   = (size_t)Dd * Dd * sizeof(unsigned short);  // 512 KiB
    const size_t ait_bytes  = (size_t)M * sizeof(float);                 // 256 KiB
    const size_t part_bytes = (size_t)B * chunks * Dd * sizeof(float);   // 512 KiB

    if (ws_size >= wb_bytes + ait_bytes) {
        unsigned short* Wb = (unsigned short*)d_ws;
        float* ait = (float*)((char*)d_ws + wb_bytes);
        wt_kernel<<<dim3((Dd * Dd / 4) / 256), dim3(256), 0, stream>>>(W, Wb);
        gemm_ait_mfma<<<dim3(M / 64), dim3(256), 0, stream>>>(x, Wb, bias, u, ait);
        softmax_kernel<<<dim3(B), dim3(256), 0, stream>>>(ait, T);
        if (ws_size >= wb_bytes + ait_bytes + part_bytes) {
            float* partial = (float*)((char*)d_ws + wb_bytes + ait_bytes);
            pool_partial_kernel<<<dim3(B * chunks), dim3(256), 0, stream>>>(x, ait, partial, T);
            pool_reduce_kernel<<<dim3(B), dim3(256), 0, stream>>>(partial, out, chunks);
        } else {
            hipMemsetAsync(d_out, 0, (size_t)out_size * sizeof(float), stream);
            pool_atomic_kernel<<<dim3(B * chunks), dim3(256), 0, stream>>>(x, ait, out, T);
        }
    } else {
        // tiny-workspace fallback: fp32 path
        float* ait = (float*)d_ws;
        gemm_ait_f32<<<dim3(M / 64), dim3(256), 0, stream>>>(x, W, bias, u, ait);
        softmax_kernel<<<dim3(B), dim3(256), 0, stream>>>(ait, T);
        hipMemsetAsync(d_out, 0, (size_t)out_size * sizeof(float), stream);
        pool_atomic_kernel<<<dim3(B * chunks), dim3(256), 0, stream>>>(x, ait, out, T);
    }
}

// Round 6
// 265.342 us; speedup vs baseline: 2.3053x; 1.0858x over previous
//
#include <hip/hip_runtime.h>
#include <math.h>

#define D_DIM 512

typedef short short8v __attribute__((ext_vector_type(8)));
typedef unsigned short ushort8v __attribute__((ext_vector_type(8)));
typedef float f32x16 __attribute__((ext_vector_type(16)));

__device__ inline unsigned short f2bf(float f) {
    union { float f; unsigned int u; } a; a.f = f;
    unsigned int u = a.u;
    unsigned int r = (u + 0x7fffu + ((u >> 16) & 1u)) >> 16;  // RNE
    return (unsigned short)r;
}

// fast tanh: 1 - 2/(e^{2y}+1); saturates correctly (inf -> 1, 0 -> -1)
__device__ inline float fast_tanh(float y) {
    float e2 = __expf(2.f * y);
    return 1.f - __fdividef(2.f, e2 + 1.f);
}

// ---- W -> Wb: transpose to [e][k] and convert to bf16 ----
__global__ __launch_bounds__(256) void wt_kernel(const float* __restrict__ W,
                                                 unsigned short* __restrict__ Wb) {
    int g = blockIdx.x * 256 + threadIdx.x;   // 0 .. 512*128-1
    int k = g >> 7;                           // W row (coalesced float4 read)
    int e4 = (g & 127) * 4;
    float4 v = *(const float4*)(W + (size_t)k * D_DIM + e4);
    Wb[(size_t)(e4 + 0) * D_DIM + k] = f2bf(v.x);
    Wb[(size_t)(e4 + 1) * D_DIM + k] = f2bf(v.y);
    Wb[(size_t)(e4 + 2) * D_DIM + k] = f2bf(v.z);
    Wb[(size_t)(e4 + 3) * D_DIM + k] = f2bf(v.w);
}

// ---- MFMA GEMM + fused tanh/dot-u epilogue, register-prefetch pipelined ----
// block: 256 thr = 4 waves; tile 64 rows x 512 cols; K staged in 32-chunks.
// wave w covers cols [w*128, w*128+128) as 2x4 tiles of 32x32 (mfma 32x32x16).
constexpr int LDE = 40;   // LDS row stride in bf16 elems = 80 B (16B-aligned)

__global__ __launch_bounds__(256, 2) void gemm_ait_mfma(
    const float* __restrict__ x, const unsigned short* __restrict__ Wb,
    const float* __restrict__ bias, const float* __restrict__ u,
    float* __restrict__ ait)
{
    __shared__ __align__(16) unsigned short xs[64 * LDE];
    __shared__ __align__(16) unsigned short wsh[512 * LDE];
    __shared__ float rowpart[4][64];

    const int tid  = threadIdx.x;
    const int wave = tid >> 6;
    const int lane = tid & 63;
    const int half = lane >> 5;      // k-half selector
    const int nl   = lane & 31;      // row/col within 32-tile
    const int m0   = blockIdx.x * 64;

    f32x16 acc[2][4];
    #pragma unroll
    for (int mi = 0; mi < 2; ++mi)
        #pragma unroll
        for (int ni = 0; ni < 4; ++ni)
            #pragma unroll
            for (int r = 0; r < 16; ++r) acc[mi][ni][r] = 0.f;

    const int xr = tid >> 2;     // x row 0..63
    const int xc = tid & 3;      // 8-elem chunk
    const float* xbase = x + (size_t)(m0 + xr) * D_DIM + xc * 8;

    // per-p W global and LDS offsets (p unrolled -> constants)
    int wg_off[8], wl_off[8];
    #pragma unroll
    for (int p = 0; p < 8; ++p) {
        int chunk = tid + p * 256;
        int e  = chunk >> 2;
        int ci = chunk & 3;
        wg_off[p] = e * D_DIM + ci * 8;
        wl_off[p] = e * LDE + ci * 8;
    }

    // prefetch stage 0
    float4 px0 = *(const float4*)(xbase);
    float4 px1 = *(const float4*)(xbase + 4);
    ushort8v pw[8];
    #pragma unroll
    for (int p = 0; p < 8; ++p)
        pw[p] = *(const ushort8v*)&Wb[wg_off[p]];

    for (int kk = 0; kk < D_DIM; kk += 32) {
        // write prefetched stage to LDS (x converted fp32->bf16 here)
        {
            ushort8v pk;
            pk[0] = f2bf(px0.x); pk[1] = f2bf(px0.y); pk[2] = f2bf(px0.z); pk[3] = f2bf(px0.w);
            pk[4] = f2bf(px1.x); pk[5] = f2bf(px1.y); pk[6] = f2bf(px1.z); pk[7] = f2bf(px1.w);
            *(ushort8v*)&xs[xr * LDE + xc * 8] = pk;
        }
        #pragma unroll
        for (int p = 0; p < 8; ++p)
            *(ushort8v*)&wsh[wl_off[p]] = pw[p];
        __syncthreads();

        // issue next stage's global loads; latency hides under the MFMA section
        if (kk + 32 < D_DIM) {
            px0 = *(const float4*)(xbase + kk + 32);
            px1 = *(const float4*)(xbase + kk + 36);
            #pragma unroll
            for (int p = 0; p < 8; ++p)
                pw[p] = *(const ushort8v*)&Wb[wg_off[p] + kk + 32];
        }

        #pragma unroll
        for (int ks = 0; ks < 2; ++ks) {      // two K=16 steps per stage
            short8v af[2], bfr[4];
            #pragma unroll
            for (int mi = 0; mi < 2; ++mi)
                af[mi] = *(const short8v*)&xs[(mi * 32 + nl) * LDE + ks * 16 + half * 8];
            #pragma unroll
            for (int ni = 0; ni < 4; ++ni)
                bfr[ni] = *(const short8v*)&wsh[(wave * 128 + ni * 32 + nl) * LDE + ks * 16 + half * 8];
            #pragma unroll
            for (int mi = 0; mi < 2; ++mi)
                #pragma unroll
                for (int ni = 0; ni < 4; ++ni)
                    acc[mi][ni] = __builtin_amdgcn_mfma_f32_32x32x16_bf16(
                        af[mi], bfr[ni], acc[mi][ni], 0, 0, 0);
        }
        __syncthreads();
    }

    // epilogue: ait[m] = sum_e tanh(C[m][e]+bias[e]) * u[e]
    // C/D layout (verified m74/m101): col = lane&31, row = (reg&3) + 8*(reg>>2) + 4*(lane>>5)
    float rowsum[2][16];
    #pragma unroll
    for (int mi = 0; mi < 2; ++mi)
        #pragma unroll
        for (int r = 0; r < 16; ++r) rowsum[mi][r] = 0.f;

    #pragma unroll
    for (int mi = 0; mi < 2; ++mi) {
        #pragma unroll
        for (int ni = 0; ni < 4; ++ni) {
            int col = wave * 128 + ni * 32 + nl;
            float be = bias[col], ue = u[col];
            #pragma unroll
            for (int r = 0; r < 16; ++r)
                rowsum[mi][r] += fast_tanh(acc[mi][ni][r] + be) * ue;
        }
    }
    // reduce across the 32 column-lanes (stays within each 32-lane half)
    #pragma unroll
    for (int mi = 0; mi < 2; ++mi)
        #pragma unroll
        for (int r = 0; r < 16; ++r) {
            float v = rowsum[mi][r];
            v += __shfl_xor(v, 1, 64);
            v += __shfl_xor(v, 2, 64);
            v += __shfl_xor(v, 4, 64);
            v += __shfl_xor(v, 8, 64);
            v += __shfl_xor(v, 16, 64);
            rowsum[mi][r] = v;
        }
    if (nl == 0) {
        #pragma unroll
        for (int mi = 0; mi < 2; ++mi)
            #pragma unroll
            for (int r = 0; r < 16; ++r) {
                int row = mi * 32 + (r & 3) + 8 * (r >> 2) + 4 * half;
                rowpart[wave][row] = rowsum[mi][r];
            }
    }
    __syncthreads();
    if (tid < 64)
        ait[m0 + tid] = rowpart[0][tid] + rowpart[1][tid] + rowpart[2][tid] + rowpart[3][tid];
}

// ---- fp32 fallback GEMM (only if workspace is unexpectedly tiny) ----
__global__ __launch_bounds__(256) void gemm_ait_f32(
    const float* __restrict__ x, const float* __restrict__ W,
    const float* __restrict__ bias, const float* __restrict__ u,
    float* __restrict__ ait)
{
    __shared__ float xsf[64][68];
    __shared__ float wshf[64][132];
    const int tid = threadIdx.x;
    const int tx = tid & 15, ty = tid >> 4;
    const int m0 = blockIdx.x * 64;
    float rowsum[4] = {0.f, 0.f, 0.f, 0.f};
    for (int e0 = 0; e0 < D_DIM; e0 += 128) {
        float acc[4][8];
        #pragma unroll
        for (int i = 0; i < 4; ++i)
            #pragma unroll
            for (int j = 0; j < 8; ++j) acc[i][j] = 0.f;
        for (int kc = 0; kc < D_DIM; kc += 64) {
            #pragma unroll
            for (int i = 0; i < 4; ++i) {
                int idx = tid + i * 256;
                int r = idx >> 4, c = (idx & 15) * 4;
                *(float4*)&xsf[r][c] = *(const float4*)(x + (size_t)(m0 + r) * D_DIM + kc + c);
            }
            #pragma unroll
            for (int i = 0; i < 8; ++i) {
                int idx = tid + i * 256;
                int r = idx >> 5, c = (idx & 31) * 4;
                *(float4*)&wshf[r][c] = *(const float4*)(W + (size_t)(kc + r) * D_DIM + e0 + c);
            }
            __syncthreads();
            #pragma unroll 4
            for (int k = 0; k < 64; ++k) {
                float xv[4];
                #pragma unroll
                for (int i = 0; i < 4; ++i) xv[i] = xsf[ty * 4 + i][k];
                float4 w0 = *(const float4*)&wshf[k][tx * 8];
                float4 w1 = *(const float4*)&wshf[k][tx * 8 + 4];
                #pragma unroll
                for (int i = 0; i < 4; ++i) {
                    acc[i][0] += xv[i] * w0.x; acc[i][1] += xv[i] * w0.y;
                    acc[i][2] += xv[i] * w0.z; acc[i][3] += xv[i] * w0.w;
                    acc[i][4] += xv[i] * w1.x; acc[i][5] += xv[i] * w1.y;
                    acc[i][6] += xv[i] * w1.z; acc[i][7] += xv[i] * w1.w;
                }
            }
            __syncthreads();
        }
        #pragma unroll
        for (int j = 0; j < 8; ++j) {
            int e = e0 + tx * 8 + j;
            float be = bias[e], ue = u[e];
            #pragma unroll
            for (int i = 0; i < 4; ++i) rowsum[i] += tanhf(acc[i][j] + be) * ue;
        }
    }
    float* red = &xsf[0][0];
    #pragma unroll
    for (int i = 0; i < 4; ++i) red[(ty * 4 + i) * 16 + tx] = rowsum[i];
    __syncthreads();
    if (tid < 64) {
        float s = 0.f;
        #pragma unroll
        for (int j = 0; j < 16; ++j) s += red[tid * 16 + j];
        ait[m0 + tid] = s;
    }
}

// ---- softmax over T (in-place, plain exp + eps, matching reference) ----
__global__ __launch_bounds__(256) void softmax_kernel(float* __restrict__ ait, int T)
{
    const int b = blockIdx.x;
    float* p = ait + (size_t)b * T;
    const int tid = threadIdx.x;
    float ev[8];
    float local = 0.f;
    #pragma unroll
    for (int i = 0; i < 8; ++i) {
        ev[i] = expf(p[tid + i * 256]);
        local += ev[i];
    }
    #pragma unroll
    for (int off = 32; off > 0; off >>= 1)
        local += __shfl_down(local, off, 64);
    __shared__ float wsum[4];
    const int wv = tid >> 6, lane = tid & 63;
    if (lane == 0) wsum[wv] = local;
    __syncthreads();
    float total = wsum[0] + wsum[1] + wsum[2] + wsum[3];
    float inv = 1.0f / (total + 1e-7f);
    #pragma unroll
    for (int i = 0; i < 8; ++i) p[tid + i * 256] = ev[i] * inv;
}

// ---- pooling: partial sums over 128-t chunks, deep-unrolled streams ----
__global__ __launch_bounds__(256) void pool_partial_kernel(
    const float* __restrict__ x, const float* __restrict__ a,
    float* __restrict__ partial, int T)
{
    const int chunks = T >> 7;               // 128 t per block -> 16 chunks
    const int b = blockIdx.x / chunks;
    const int c = blockIdx.x % chunks;
    const int tid = threadIdx.x;
    const int th = tid >> 7;                 // 2 t-streams
    const int d = (tid & 127) * 4;
    const int t0 = c * 128;

    const float* xp = x + ((size_t)b * T + t0) * D_DIM + d;
    const float* ap = a + (size_t)b * T + t0;

    float4 acc = {0.f, 0.f, 0.f, 0.f};
    #pragma unroll 8
    for (int t = th; t < 128; t += 2) {      // 64 iters/stream, 8 loads in flight
        float s = ap[t];
        float4 xv = *(const float4*)(xp + (size_t)t * D_DIM);
        acc.x += xv.x * s; acc.y += xv.y * s;
        acc.z += xv.z * s; acc.w += xv.w * s;
    }
    __shared__ float4 tmp[128];
    if (th == 1) tmp[tid & 127] = acc;
    __syncthreads();
    if (th == 0) {
        float4 o = tmp[tid];
        acc.x += o.x; acc.y += o.y; acc.z += o.z; acc.w += o.w;
        *(float4*)(partial + (size_t)blockIdx.x * D_DIM + d) = acc;
    }
}

__global__ __launch_bounds__(256) void pool_reduce_kernel(
    const float* __restrict__ partial, float* __restrict__ out, int chunks)
{
    const int b = blockIdx.x;
    const int tid = threadIdx.x;
    const int d = tid * 2;
    float2 acc = {0.f, 0.f};
    for (int c = 0; c < chunks; ++c) {
        float2 v = *(const float2*)(partial + ((size_t)b * chunks + c) * D_DIM + d);
        acc.x += v.x; acc.y += v.y;
    }
    *(float2*)(out + (size_t)b * D_DIM + d) = acc;
}

__global__ __launch_bounds__(256) void pool_atomic_kernel(
    const float* __restrict__ x, const float* __restrict__ a,
    float* __restrict__ out, int T)
{
    const int chunks = T >> 8;
    const int b = blockIdx.x / chunks;
    const int c = blockIdx.x % chunks;
    const int tid = threadIdx.x;
    const int d = tid * 2;
    const int t0 = c * 256;
    const float* xp = x + ((size_t)b * T + t0) * D_DIM + d;
    const float* ap = a + (size_t)b * T + t0;
    float2 acc = {0.f, 0.f};
    for (int t = 0; t < 256; ++t) {
        float s = ap[t];
        float2 xv = *(const float2*)(xp + (size_t)t * D_DIM);
        acc.x += xv.x * s; acc.y += xv.y * s;
    }
    float* o = out + (size_t)b * D_DIM + d;
    atomicAdd(o + 0, acc.x);
    atomicAdd(o + 1, acc.y);
}

extern "C" void kernel_launch(void* const* d_in, const int* in_sizes, int n_in,
                              void* d_out, int out_size, void* d_ws, size_t ws_size,
                              hipStream_t stream)
{
    const float* x    = (const float*)d_in[0];
    const float* W    = (const float*)d_in[1];
    const float* bias = (const float*)d_in[2];
    const float* u    = (const float*)d_in[3];
    float* out = (float*)d_out;

    const int Dd = in_sizes[2];          // 512
    const int M  = in_sizes[0] / Dd;     // 65536
    const int B  = out_size / Dd;        // 32
    const int T  = M / B;                // 2048
    const int chunks = T >> 7;           // 16

    const size_t wb_bytes   = (size_t)Dd * Dd * sizeof(unsigned short);  // 512 KiB
    const size_t ait_bytes  = (size_t)M * sizeof(float);                 // 256 KiB
    const size_t part_bytes = (size_t)B * chunks * Dd * sizeof(float);   // 1 MiB

    if (ws_size >= wb_bytes + ait_bytes) {
        unsigned short* Wb = (unsigned short*)d_ws;
        float* ait = (float*)((char*)d_ws + wb_bytes);
        wt_kernel<<<dim3((Dd * Dd / 4) / 256), dim3(256), 0, stream>>>(W, Wb);
        gemm_ait_mfma<<<dim3(M / 64), dim3(256), 0, stream>>>(x, Wb, bias, u, ait);
        softmax_kernel<<<dim3(B), dim3(256), 0, stream>>>(ait, T);
        if (ws_size >= wb_bytes + ait_bytes + part_bytes) {
            float* partial = (float*)((char*)d_ws + wb_bytes + ait_bytes);
            pool_partial_kernel<<<dim3(B * chunks), dim3(256), 0, stream>>>(x, ait, partial, T);
            pool_reduce_kernel<<<dim3(B), dim3(256), 0, stream>>>(partial, out, chunks);
        } else {
            hipMemsetAsync(d_out, 0, (size_t)out_size * sizeof(float), stream);
            pool_atomic_kernel<<<dim3(B * (T >> 8)), dim3(256), 0, stream>>>(x, ait, out, T);
        }
    } else {
        // tiny-workspace fallback: fp32 path
        float* ait = (float*)d_ws;
        gemm_ait_f32<<<dim3(M / 64), dim3(256), 0, stream>>>(x, W, bias, u, ait);
        softmax_kernel<<<dim3(B), dim3(256), 0, stream>>>(ait, T);
        hipMemsetAsync(d_out, 0, (size_t)out_size * sizeof(float), stream);
        pool_atomic_kernel<<<dim3(B * (T >> 8)), dim3(256), 0, stream>>>(x, ait, out, T);
    }
}